// Round 6
// baseline (93.278 us; speedup 1.0000x reference)
//
#include <hip/hip_runtime.h>
#include <hip/hip_fp16.h>

#define CELL 128
#define STEPS 20
#define MAGIC 0x5F3A9C21u

typedef _Float16 half8_t __attribute__((ext_vector_type(8)));
typedef float    floatx4 __attribute__((ext_vector_type(4)));

// ---------------- workspace layout ----------------
// WS_GX : [20][512] f32 gates_x with b_ih+b_hh folded, idx t*512 + cell*4 + tau
// WS_WHH: [16][512] half8 W_hh fragments (uint4), g = tau*4+kc, m = thread id
// WS_FLG: 80 u32 magic slots: [0..15] whh, [16..79] gx (all 20 steps)
#define WS_GX    0
#define WS_WHH   40960
#define WS_FLG   172032
#define WS_NEED  (172032 + 80 * 4)

__device__ __forceinline__ unsigned packf2(float x, float y) {
    typedef _Float16 h2 __attribute__((ext_vector_type(2)));
    h2 h = { (_Float16)x, (_Float16)y };
    return __builtin_bit_cast(unsigned, h);
}
__device__ __forceinline__ float fdot2u(unsigned a, unsigned b, float c) {
    typedef _Float16 h2 __attribute__((ext_vector_type(2)));
#if __has_builtin(__builtin_amdgcn_fdot2)
    return __builtin_amdgcn_fdot2(__builtin_bit_cast(h2, a), __builtin_bit_cast(h2, b), c, false);
#else
    h2 x = __builtin_bit_cast(h2, a), y = __builtin_bit_cast(h2, b);
    return fmaf((float)x[0], (float)y[0], fmaf((float)x[1], (float)y[1], c));
#endif
}
__device__ __forceinline__ float fastrcp(float x) {
#if __has_builtin(__builtin_amdgcn_rcpf)
    return __builtin_amdgcn_rcpf(x);
#else
    return 1.0f / x;
#endif
}
__device__ __forceinline__ float sig_rcp(float x)  { return fastrcp(1.0f + __expf(-x)); }
__device__ __forceinline__ float tanh_rcp(float x) { return fmaf(2.0f, fastrcp(1.0f + __expf(-2.0f * x)), -1.0f); }
__device__ __forceinline__ half8_t cvt8(const float* p) {
    const float4* p4 = (const float4*)p;
    float4 a = p4[0], b = p4[1];
    return half8_t{ (_Float16)a.x, (_Float16)a.y, (_Float16)a.z, (_Float16)a.w,
                    (_Float16)b.x, (_Float16)b.y, (_Float16)b.z, (_Float16)b.w };
}

// Rare-path fallback: consumer computes all gx itself into ws (global),
// using sx LDS staging. Correct regardless of producer scheduling.
__device__ static void self_gx(float (*sx)[CELL], const int* net,
                               const float* emb_start, const float* emb_keys,
                               const float* W_ih, const float* b_ih, const float* b_hh,
                               float* gxp, int tid)
{
    for (int i = tid; i < STEPS * CELL; i += 512) {
        const int t = i >> 7, k = i & 127;
        sx[t][k] = (t == 0) ? emb_start[k]
                 : emb_keys[((((t - 1) & 3) * 6) + net[t - 1]) * CELL + k];
    }
    __syncthreads();
    const int row = tid, tau = row >> 7, cell = row & 127;
    const float4* w4 = (const float4*)(W_ih + row * CELL);
    const float bias = b_ih[row] + b_hh[row];
    for (int t = 0; t < STEPS; ++t) {
        const float4* x4 = (const float4*)sx[t];
        float a = 0.f, b = 0.f, c = 0.f, d = 0.f;
#pragma unroll 8
        for (int k = 0; k < 32; ++k) {
            float4 wv = w4[k], xv = x4[k];
            a = fmaf(wv.x, xv.x, a); b = fmaf(wv.y, xv.y, b);
            c = fmaf(wv.z, xv.z, c); d = fmaf(wv.w, xv.w, d);
        }
        gxp[t * 512 + cell * 4 + tau] = (a + b) + (c + d) + bias;
    }
    __threadfence();
    __syncthreads();
}

// ============================================================================
// Single regular launch, 81 blocks x 512 (R4/R5 structure, proven 92.5us).
// R6 change (single variable): SINGLE-PHASE gating. Producers flag once
// after all 20 steps; consumer waits once, preloads ALL 20 gx into
// registers (80 VGPR), then runs the fully-unrolled recurrence with zero
// gates, zero vmem, zero mid-loop fences. This removes R5's t==9 gate
// (syncthreads+fence+64-slot poll on the critical path) and the step-9
// vmcnt(0) drain against the batch-B loads (~0.3-0.5us combined). The
// later flag (~0.3us) is covered by the consumer's pre-loop work.
// ============================================================================
extern "C" __global__ void __launch_bounds__(512, 1)
nas_fused_kernel(const int* __restrict__ net,
                 const float* __restrict__ emb_start,
                 const float* __restrict__ emb_keys,
                 const float* __restrict__ fc_W,
                 const float* __restrict__ fc_b,
                 const float* __restrict__ W_ih,
                 const float* __restrict__ W_hh,
                 const float* __restrict__ b_ih,
                 const float* __restrict__ b_hh,
                 unsigned char* __restrict__ ws,
                 float* __restrict__ out)
{
    const int b   = blockIdx.x;
    const int tid = threadIdx.x;

    __shared__ __align__(16) float     sx[STEPS][CELL];   // producers + fallback
    __shared__ __align__(16) _Float16  hbuf[2 * 128];
    __shared__ __align__(16) unsigned  s_fcw2[24 * 64];
    __shared__ float s_fcb[24];
    __shared__ float llog[STEPS * 8];
    __shared__ int   s_fail[2];

    unsigned* flg = (unsigned*)(ws + WS_FLG);
    float*    gxp = (float*)(ws + WS_GX);

    if (b >= 1 && b <= 64) {
        // ---------------- gx producers: 8 rows/block, one row per wave ------
        for (int i = tid; i < STEPS * CELL; i += 512) {
            const int t = i >> 7, k = i & 127;
            sx[t][k] = (t == 0) ? emb_start[k]
                     : emb_keys[((((t - 1) & 3) * 6) + net[t - 1]) * CELL + k];
        }
        const int row  = (b - 1) * 8 + (tid >> 6);
        const int lane = tid & 63;
        const float2 w = ((const float2*)W_ih)[row * 64 + lane];
        const float bias = b_ih[row] + b_hh[row];
        __syncthreads();
        const int tau = row >> 7, cell = row & 127;
#pragma unroll
        for (int t = 0; t < STEPS; ++t) {
            const float2 xv = *(const float2*)&sx[t][lane * 2];
            float p = fmaf(w.x, xv.x, w.y * xv.y);
            p += __shfl_down(p, 32); p += __shfl_down(p, 16);
            p += __shfl_down(p, 8);  p += __shfl_down(p, 4);
            p += __shfl_down(p, 2);  p += __shfl_down(p, 1);
            if (lane == 0) gxp[t * 512 + cell * 4 + tau] = p + bias;
        }
        __syncthreads();   // all waves' stores drained
        if (tid == 0)
            __hip_atomic_store(&flg[16 + (b - 1)], MAGIC, __ATOMIC_RELEASE, __HIP_MEMORY_SCOPE_AGENT);
        return;
    } else if (b >= 65) {
        // ---------------- W_hh f16 fragment pack ----------------------------
        const int F   = (b - 65) * 512 + tid;        // 0..8191
        const int g   = F >> 9;                      // tau*4 + kc
        const int m   = F & 511;
        const int tau = g >> 2, kc = g & 3;
        const int rr  = ((m >> 6) << 4) + (m & 15);
        const int qd  = (m >> 4) & 3;
        const int k0  = kc * 32 + qd * 8;
        half8_t h8 = cvt8(W_hh + (tau * 128 + rr) * CELL + k0);
        ((uint4*)(ws + WS_WHH))[g * 512 + m] = __builtin_bit_cast(uint4, h8);
        __syncthreads();
        if (tid == 0)
            __hip_atomic_store(&flg[b - 65], MAGIC, __ATOMIC_RELEASE, __HIP_MEMORY_SCOPE_AGENT);
        return;
    }

    // ======================= consumer (block 0) =============================
    const int t0   = tid;
    const int wv   = t0 >> 6;
    const int lane = t0 & 63;
    const int quad = lane >> 4;
    const int lcol = lane & 15;
    const int rr0  = (wv << 4) + lcol;

    if (tid < 2) s_fail[tid] = 0;
    {   // fc pack into own LDS (cold 6 KB; overlaps whh wait)
        const float2* fw2 = (const float2*)fc_W;
        for (int i = tid; i < 24 * 64; i += 512) {
            const float2 w = fw2[i];
            s_fcw2[i] = packf2(w.x, w.y);
        }
        if (tid < 24)  s_fcb[tid] = fc_b[tid];
        if (tid < 128) hbuf[128 + tid] = (_Float16)0.0f;  // h(-1)=0 (parity 1)
    }

    // ---- wait: W_hh fragments ready ----
    if (tid < 16) {
        int budget = 1 << 17;
        while (__hip_atomic_load(&flg[tid], __ATOMIC_RELAXED, __HIP_MEMORY_SCOPE_AGENT) != MAGIC)
            if (--budget == 0) { atomicOr(&s_fail[0], 1); break; }
    }
    __syncthreads();                                  // also publishes fc/hbuf LDS
    __builtin_amdgcn_fence(__ATOMIC_ACQUIRE, "agent");

    half8_t bf0[4], bf1[4], bf2[4], bf3[4];
    if (s_fail[0] == 0) {
        const uint4* ws_whh = (const uint4*)(ws + WS_WHH);
#pragma unroll
        for (int kc = 0; kc < 4; ++kc) {
            bf0[kc] = __builtin_bit_cast(half8_t, ws_whh[(0 * 4 + kc) * 512 + t0]);
            bf1[kc] = __builtin_bit_cast(half8_t, ws_whh[(1 * 4 + kc) * 512 + t0]);
            bf2[kc] = __builtin_bit_cast(half8_t, ws_whh[(2 * 4 + kc) * 512 + t0]);
            bf3[kc] = __builtin_bit_cast(half8_t, ws_whh[(3 * 4 + kc) * 512 + t0]);
        }
    } else {                                          // timeout: pack ourselves
#pragma unroll
        for (int kc = 0; kc < 4; ++kc) {
            const int k0 = kc * 32 + quad * 8;
            bf0[kc] = cvt8(W_hh + (0 * 128 + rr0) * CELL + k0);
            bf1[kc] = cvt8(W_hh + (1 * 128 + rr0) * CELL + k0);
            bf2[kc] = cvt8(W_hh + (2 * 128 + rr0) * CELL + k0);
            bf3[kc] = cvt8(W_hh + (3 * 128 + rr0) * CELL + k0);
        }
    }

    // ---- wait: all gx ready (single phase) ----
    if (tid < 64) {
        int budget = 1 << 18;
        while (__hip_atomic_load(&flg[16 + tid], __ATOMIC_RELAXED, __HIP_MEMORY_SCOPE_AGENT) != MAGIC)
            if (--budget == 0) { atomicOr(&s_fail[1], 1); break; }
    }
    __syncthreads();
    __builtin_amdgcn_fence(__ATOMIC_ACQUIRE, "agent");
    if (s_fail[1])                                     // timeout: compute all gx
        self_gx(sx, net, emb_start, emb_keys, W_ih, b_ih, b_hh, gxp, tid);

    const float* ws_gx = (const float*)(ws + WS_GX);
    // ---- ALL 20 gx into registers: one load batch, one implicit wait ----
    floatx4 gxr[STEPS];
#pragma unroll
    for (int i = 0; i < STEPS; ++i)
        gxr[i] = *(const floatx4*)&ws_gx[i * 512 + rr0 * 4];
    float c = 0.0f;

    // ====== proven recurrence loop (fully unrolled, no vmem, no gates) ======
#pragma unroll
    for (int t = 0; t < STEPS; ++t) {
        const floatx4 gx = gxr[t];                     // static index (unrolled)
        const uint4* hp4 = (const uint4*)(hbuf + (((t + 1) & 1) << 7));  // h(t-1)

        floatx4 a0a = { gx[0], 0, 0, 0 }, a0b = { 0, 0, 0, 0 };
        floatx4 a1a = { gx[1], 0, 0, 0 }, a1b = { 0, 0, 0, 0 };
        floatx4 a2a = { gx[2], 0, 0, 0 }, a2b = { 0, 0, 0, 0 };
        floatx4 a3a = { gx[3], 0, 0, 0 }, a3b = { 0, 0, 0, 0 };
        {
            uint4 u0 = hp4[(0 << 2) + quad], u1 = hp4[(1 << 2) + quad];
            uint4 u2 = hp4[(2 << 2) + quad], u3 = hp4[(3 << 2) + quad];
            half8_t f0 = __builtin_bit_cast(half8_t, u0), f1 = __builtin_bit_cast(half8_t, u1);
            half8_t f2 = __builtin_bit_cast(half8_t, u2), f3 = __builtin_bit_cast(half8_t, u3);
            a0a = __builtin_amdgcn_mfma_f32_16x16x32_f16(f0, bf0[0], a0a, 0, 0, 0);
            a1a = __builtin_amdgcn_mfma_f32_16x16x32_f16(f0, bf1[0], a1a, 0, 0, 0);
            a2a = __builtin_amdgcn_mfma_f32_16x16x32_f16(f0, bf2[0], a2a, 0, 0, 0);
            a3a = __builtin_amdgcn_mfma_f32_16x16x32_f16(f0, bf3[0], a3a, 0, 0, 0);
            a0b = __builtin_amdgcn_mfma_f32_16x16x32_f16(f1, bf0[1], a0b, 0, 0, 0);
            a1b = __builtin_amdgcn_mfma_f32_16x16x32_f16(f1, bf1[1], a1b, 0, 0, 0);
            a2b = __builtin_amdgcn_mfma_f32_16x16x32_f16(f1, bf2[1], a2b, 0, 0, 0);
            a3b = __builtin_amdgcn_mfma_f32_16x16x32_f16(f1, bf3[1], a3b, 0, 0, 0);
            a0a = __builtin_amdgcn_mfma_f32_16x16x32_f16(f2, bf0[2], a0a, 0, 0, 0);
            a1a = __builtin_amdgcn_mfma_f32_16x16x32_f16(f2, bf1[2], a1a, 0, 0, 0);
            a2a = __builtin_amdgcn_mfma_f32_16x16x32_f16(f2, bf2[2], a2a, 0, 0, 0);
            a3a = __builtin_amdgcn_mfma_f32_16x16x32_f16(f2, bf3[2], a3a, 0, 0, 0);
            a0b = __builtin_amdgcn_mfma_f32_16x16x32_f16(f3, bf0[3], a0b, 0, 0, 0);
            a1b = __builtin_amdgcn_mfma_f32_16x16x32_f16(f3, bf1[3], a1b, 0, 0, 0);
            a2b = __builtin_amdgcn_mfma_f32_16x16x32_f16(f3, bf2[3], a2b, 0, 0, 0);
            a3b = __builtin_amdgcn_mfma_f32_16x16x32_f16(f3, bf3[3], a3b, 0, 0, 0);
        }

        // heads of step t-1 on waves 0-5 quad 1, in the MFMA shadow (LDS reads)
        if (t >= 1 && wv < 6 && quad == 1) {
            const int li = lcol;
            const int hg = ((t - 1) & 3) * 6 + wv;
            const unsigned* hb = (const unsigned*)(hbuf + (((t + 1) & 1) << 7));
            const uint4 wpv = *(const uint4*)(s_fcw2 + hg * 64 + li * 4);
            float p = fdot2u(hb[li * 4],     wpv.x, 0.0f);
            p = fdot2u(hb[li * 4 + 1], wpv.y, p);
            p = fdot2u(hb[li * 4 + 2], wpv.z, p);
            p = fdot2u(hb[li * 4 + 3], wpv.w, p);
            p += __shfl_down(p, 8); p += __shfl_down(p, 4);
            p += __shfl_down(p, 2); p += __shfl_down(p, 1);
            if (li == 0) llog[(t - 1) * 8 + wv] = p + s_fcb[hg];
        }

        // full elementwise on every lane (gx in acc; no shuffles)
        {
            float ig = sig_rcp (a0a[0] + a0b[0]);
            float fg = sig_rcp (a1a[0] + a1b[0]);
            float gg = tanh_rcp(a2a[0] + a2b[0]);
            float og = sig_rcp (a3a[0] + a3b[0]);
            c = fg * c + ig * gg;
            float h = og * tanh_rcp(c);
            if (quad == 0)
                hbuf[((t & 1) << 7) + rr0] = (_Float16)h;
        }

        __syncthreads();
    }

    // ======== epilogue: head(19) + all 20 softmaxes ========
    if (wv < 6 && quad == 1) {
        const int li = lcol;
        const int hg = (19 & 3) * 6 + wv;
        const unsigned* hb = (const unsigned*)(hbuf + 128);   // h(19), parity 1
        const uint4 wpv = *(const uint4*)(s_fcw2 + hg * 64 + li * 4);
        float p = fdot2u(hb[li * 4],     wpv.x, 0.0f);
        p = fdot2u(hb[li * 4 + 1], wpv.y, p);
        p = fdot2u(hb[li * 4 + 2], wpv.z, p);
        p = fdot2u(hb[li * 4 + 3], wpv.w, p);
        p += __shfl_down(p, 8); p += __shfl_down(p, 4);
        p += __shfl_down(p, 2); p += __shfl_down(p, 1);
        if (li == 0) llog[19 * 8 + wv] = p + s_fcb[hg];
    }
    __syncthreads();
    if (t0 < STEPS * 6) {
        const int s = t0 / 6, k = t0 - s * 6;
        const float* L = llog + s * 8;
        float l0 = L[0], l1 = L[1], l2 = L[2], l3 = L[3], l4 = L[4], l5 = L[5];
        float m = fmaxf(fmaxf(fmaxf(l0, l1), fmaxf(l2, l3)), fmaxf(l4, l5));
        float e0 = __expf(l0 - m), e1 = __expf(l1 - m), e2 = __expf(l2 - m);
        float e3 = __expf(l3 - m), e4 = __expf(l4 - m), e5 = __expf(l5 - m);
        float sum = ((e0 + e1) + (e2 + e3)) + (e4 + e5);
        float mine = (k == 0) ? e0 : (k == 1) ? e1 : (k == 2) ? e2
                   : (k == 3) ? e3 : (k == 4) ? e4 : e5;
        out[t0] = mine / sum;
    }

    // reset flag slots for the next replay (producers all done: we waited)
    if (t0 < 80) flg[t0] = 0u;
    __syncthreads();
    if (t0 == 0) __builtin_amdgcn_fence(__ATOMIC_RELEASE, "agent");
}

// ============================================================================
// Fallback: proven mono kernel (used only if ws is too small).
// ============================================================================
extern "C" __global__ void __launch_bounds__(512, 1)
nas_policy_mono(const int* __restrict__ net,
                const float* __restrict__ emb_start,
                const float* __restrict__ emb_keys,
                const float* __restrict__ fc_W,
                const float* __restrict__ fc_b,
                const float* __restrict__ W_ih,
                const float* __restrict__ W_hh,
                const float* __restrict__ b_ih,
                const float* __restrict__ b_hh,
                float* __restrict__ out)
{
    const int t0   = threadIdx.x;
    const int wv   = t0 >> 6;
    const int lane = t0 & 63;
    const int quad = lane >> 4;
    const int lcol = lane & 15;

    __shared__ __align__(16) unsigned  s_xv2[32 * 68];
    __shared__ __align__(16) float     s_gx[STEPS * 512];
    __shared__ __align__(16) _Float16  hbuf[2 * 128];
    __shared__ unsigned s_fcw2[24 * 64];
    __shared__ float    s_fcb[24];
    __shared__ float    llog[STEPS * 8];

    for (int i = t0; i < STEPS * 64; i += 512) {
        const int m = i >> 6, j = i & 63;
        const float2* src = (m == 0) ? (const float2*)emb_start
            : (const float2*)(emb_keys + ((((m - 1) & 3) * 6) + net[m - 1]) * CELL);
        float2 v = src[j];
        s_xv2[m * 68 + j] = packf2(v.x, v.y);
    }
    {
        const float2* fw2 = (const float2*)fc_W;
        for (int i = t0; i < 24 * 64; i += 512) { float2 w = fw2[i]; s_fcw2[i] = packf2(w.x, w.y); }
    }
    if (t0 < 24)  s_fcb[t0] = fc_b[t0];
    if (t0 < 128) hbuf[128 + t0] = (_Float16)0.0f;

    const int rr0 = (wv << 4) + lcol;
    float biasx[4];
#pragma unroll
    for (int tau = 0; tau < 4; ++tau) {
        const int r = tau * 128 + rr0;
        biasx[tau] = b_ih[r] + b_hh[r];
    }

    __syncthreads();

    {
        half8_t bw[4][4];
#pragma unroll
        for (int kc = 0; kc < 4; ++kc) {
            const int k0 = kc * 32 + quad * 8;
#pragma unroll
            for (int tau = 0; tau < 4; ++tau)
                bw[kc][tau] = cvt8(W_ih + (tau * 128 + rr0) * CELL + k0);
        }
        floatx4 ax0[4] = { {0,0,0,0}, {0,0,0,0}, {0,0,0,0}, {0,0,0,0} };
        floatx4 ax1[4] = { {0,0,0,0}, {0,0,0,0}, {0,0,0,0}, {0,0,0,0} };
#pragma unroll
        for (int kc = 0; kc < 4; ++kc) {
            uint4 u0 = *(const uint4*)&s_xv2[lcol * 68 + kc * 16 + quad * 4];
            uint4 u1 = *(const uint4*)&s_xv2[(16 + lcol) * 68 + kc * 16 + quad * 4];
            half8_t a0f = __builtin_bit_cast(half8_t, u0);
            half8_t a1f = __builtin_bit_cast(half8_t, u1);
#pragma unroll
            for (int tau = 0; tau < 4; ++tau) {
                ax0[tau] = __builtin_amdgcn_mfma_f32_16x16x32_f16(a0f, bw[kc][tau], ax0[tau], 0, 0, 0);
                ax1[tau] = __builtin_amdgcn_mfma_f32_16x16x32_f16(a1f, bw[kc][tau], ax1[tau], 0, 0, 0);
            }
        }
#pragma unroll
        for (int tau = 0; tau < 4; ++tau) {
#pragma unroll
            for (int reg = 0; reg < 4; ++reg)
                s_gx[(quad * 4 + reg) * 512 + rr0 * 4 + tau] = ax0[tau][reg] + biasx[tau];
            if (quad == 0) {
#pragma unroll
                for (int reg = 0; reg < 4; ++reg)
                    s_gx[(16 + reg) * 512 + rr0 * 4 + tau] = ax1[tau][reg] + biasx[tau];
            }
        }
    }

    half8_t bf0[4], bf1[4], bf2[4], bf3[4];
#pragma unroll
    for (int kc = 0; kc < 4; ++kc) {
        const int k0 = kc * 32 + quad * 8;
        bf0[kc] = cvt8(W_hh + (0 * 128 + rr0) * CELL + k0);
        bf1[kc] = cvt8(W_hh + (1 * 128 + rr0) * CELL + k0);
        bf2[kc] = cvt8(W_hh + (2 * 128 + rr0) * CELL + k0);
        bf3[kc] = cvt8(W_hh + (3 * 128 + rr0) * CELL + k0);
    }

    float c = 0.0f;
    __syncthreads();

    for (int t = 0; t < STEPS; ++t) {
        const uint4* hp4 = (const uint4*)(hbuf + (((t + 1) & 1) << 7));
        floatx4 gx = *(const floatx4*)&s_gx[t * 512 + rr0 * 4];
        floatx4 a0a = {0,0,0,0}, a0b = {0,0,0,0}, a1a = {0,0,0,0}, a1b = {0,0,0,0};
        floatx4 a2a = {0,0,0,0}, a2b = {0,0,0,0}, a3a = {0,0,0,0}, a3b = {0,0,0,0};
        {
            uint4 u0 = hp4[(0 << 2) + quad], u1 = hp4[(1 << 2) + quad];
            uint4 u2 = hp4[(2 << 2) + quad], u3 = hp4[(3 << 2) + quad];
            half8_t f0 = __builtin_bit_cast(half8_t, u0), f1 = __builtin_bit_cast(half8_t, u1);
            half8_t f2 = __builtin_bit_cast(half8_t, u2), f3 = __builtin_bit_cast(half8_t, u3);
            a0a = __builtin_amdgcn_mfma_f32_16x16x32_f16(f0, bf0[0], a0a, 0, 0, 0);
            a1a = __builtin_amdgcn_mfma_f32_16x16x32_f16(f0, bf1[0], a1a, 0, 0, 0);
            a2a = __builtin_amdgcn_mfma_f32_16x16x32_f16(f0, bf2[0], a2a, 0, 0, 0);
            a3a = __builtin_amdgcn_mfma_f32_16x16x32_f16(f0, bf3[0], a3a, 0, 0, 0);
            a0b = __builtin_amdgcn_mfma_f32_16x16x32_f16(f1, bf0[1], a0b, 0, 0, 0);
            a1b = __builtin_amdgcn_mfma_f32_16x16x32_f16(f1, bf1[1], a1b, 0, 0, 0);
            a2b = __builtin_amdgcn_mfma_f32_16x16x32_f16(f1, bf2[1], a2b, 0, 0, 0);
            a3b = __builtin_amdgcn_mfma_f32_16x16x32_f16(f1, bf3[1], a3b, 0, 0, 0);
            a0a = __builtin_amdgcn_mfma_f32_16x16x32_f16(f2, bf0[2], a0a, 0, 0, 0);
            a1a = __builtin_amdgcn_mfma_f32_16x16x32_f16(f2, bf1[2], a1a, 0, 0, 0);
            a2a = __builtin_amdgcn_mfma_f32_16x16x32_f16(f2, bf2[2], a2a, 0, 0, 0);
            a3a = __builtin_amdgcn_mfma_f32_16x16x32_f16(f2, bf3[2], a3a, 0, 0, 0);
            a0b = __builtin_amdgcn_mfma_f32_16x16x32_f16(f3, bf0[3], a0b, 0, 0, 0);
            a1b = __builtin_amdgcn_mfma_f32_16x16x32_f16(f3, bf1[3], a1b, 0, 0, 0);
            a2b = __builtin_amdgcn_mfma_f32_16x16x32_f16(f3, bf2[3], a2b, 0, 0, 0);
            a3b = __builtin_amdgcn_mfma_f32_16x16x32_f16(f3, bf3[3], a3b, 0, 0, 0);
        }

        if (t >= 1 && wv < 6 && quad == 1) {
            const int li = lcol;
            const int hg = ((t - 1) & 3) * 6 + wv;
            const unsigned* hb = (const unsigned*)(hbuf + (((t + 1) & 1) << 7));
            const unsigned* wp = s_fcw2 + hg * 64 + li * 4;
            float p = fdot2u(hb[li * 4],     wp[0], 0.0f);
            p = fdot2u(hb[li * 4 + 1], wp[1], p);
            p = fdot2u(hb[li * 4 + 2], wp[2], p);
            p = fdot2u(hb[li * 4 + 3], wp[3], p);
            p += __shfl_down(p, 8); p += __shfl_down(p, 4);
            p += __shfl_down(p, 2); p += __shfl_down(p, 1);
            if (li == 0) llog[(t - 1) * 8 + wv] = p + s_fcb[hg];
        }

        {
            float ig = sig_rcp (a0a[0] + a0b[0] + gx[0]);
            float fg = sig_rcp (a1a[0] + a1b[0] + gx[1]);
            float gg = tanh_rcp(a2a[0] + a2b[0] + gx[2]);
            float og = sig_rcp (a3a[0] + a3b[0] + gx[3]);
            c = fg * c + ig * gg;
            float h = og * tanh_rcp(c);
            if (quad == 0)
                hbuf[((t & 1) << 7) + rr0] = (_Float16)h;
        }

        __syncthreads();
    }

    if (wv < 6 && quad == 1) {
        const int li = lcol;
        const int hg = (19 & 3) * 6 + wv;
        const unsigned* hb = (const unsigned*)(hbuf + 128);
        const unsigned* wp = s_fcw2 + hg * 64 + li * 4;
        float p = fdot2u(hb[li * 4],     wp[0], 0.0f);
        p = fdot2u(hb[li * 4 + 1], wp[1], p);
        p = fdot2u(hb[li * 4 + 2], wp[2], p);
        p = fdot2u(hb[li * 4 + 3], wp[3], p);
        p += __shfl_down(p, 8); p += __shfl_down(p, 4);
        p += __shfl_down(p, 2); p += __shfl_down(p, 1);
        if (li == 0) llog[19 * 8 + wv] = p + s_fcb[hg];
    }
    __syncthreads();
    if (t0 < STEPS * 6) {
        const int s = t0 / 6, k = t0 - s * 6;
        const float* L = llog + s * 8;
        float l0 = L[0], l1 = L[1], l2 = L[2], l3 = L[3], l4 = L[4], l5 = L[5];
        float m = fmaxf(fmaxf(fmaxf(l0, l1), fmaxf(l2, l3)), fmaxf(l4, l5));
        float e0 = __expf(l0 - m), e1 = __expf(l1 - m), e2 = __expf(l2 - m);
        float e3 = __expf(l3 - m), e4 = __expf(l4 - m), e5 = __expf(l5 - m);
        float sum = ((e0 + e1) + (e2 + e3)) + (e4 + e5);
        float mine = (k == 0) ? e0 : (k == 1) ? e1 : (k == 2) ? e2
                   : (k == 3) ? e3 : (k == 4) ? e4 : e5;
        out[t0] = mine / sum;
    }
}

extern "C" void kernel_launch(void* const* d_in, const int* in_sizes, int n_in,
                              void* d_out, int out_size, void* d_ws, size_t ws_size,
                              hipStream_t stream) {
    (void)in_sizes; (void)n_in; (void)out_size;
    const int*   net       = (const int*)d_in[0];
    // d_in[1] = reward, unused in forward
    const float* emb_start = (const float*)d_in[2];
    const float* emb_keys  = (const float*)d_in[3];
    const float* fc_W      = (const float*)d_in[4];
    const float* fc_b      = (const float*)d_in[5];
    const float* W_ih      = (const float*)d_in[6];
    const float* W_hh      = (const float*)d_in[7];
    const float* b_ih      = (const float*)d_in[8];
    const float* b_hh      = (const float*)d_in[9];
    float*       out       = (float*)d_out;

    if (d_ws != nullptr && ws_size >= (size_t)WS_NEED) {
        unsigned char* ws = (unsigned char*)d_ws;
        hipLaunchKernelGGL(nas_fused_kernel, dim3(81), dim3(512), 0, stream,
                           net, emb_start, emb_keys, fc_W, fc_b,
                           W_ih, W_hh, b_ih, b_hh, ws, out);
    } else {
        hipLaunchKernelGGL(nas_policy_mono, dim3(1), dim3(512), 0, stream,
                           net, emb_start, emb_keys, fc_W, fc_b,
                           W_ih, W_hh, b_ih, b_hh, out);
    }
}

// Round 7
// 91.752 us; speedup vs baseline: 1.0166x; 1.0166x over previous
//
#include <hip/hip_runtime.h>
#include <hip/hip_fp16.h>

#define CELL 128
#define STEPS 20
#define MAGIC 0x5F3A9C21u

typedef _Float16 half8_t __attribute__((ext_vector_type(8)));
typedef float    floatx4 __attribute__((ext_vector_type(4)));

// ---------------- workspace layout ----------------
// WS_GX : [20][512] f32 gates_x with b_ih+b_hh folded, idx t*512 + cell*4 + tau
// WS_WHH: [16][512] half8 W_hh fragments (uint4), g = tau*4+kc, m = thread id
// WS_FLG: 144 u32 magic slots: [0..15] whh, [16..79] gxA(t<10), [80..143] gxB
#define WS_GX    0
#define WS_WHH   40960
#define WS_FLG   172032
#define WS_NEED  (172032 + 144 * 4)

__device__ __forceinline__ unsigned packf2(float x, float y) {
    typedef _Float16 h2 __attribute__((ext_vector_type(2)));
    h2 h = { (_Float16)x, (_Float16)y };
    return __builtin_bit_cast(unsigned, h);
}
__device__ __forceinline__ float fdot2u(unsigned a, unsigned b, float c) {
    typedef _Float16 h2 __attribute__((ext_vector_type(2)));
#if __has_builtin(__builtin_amdgcn_fdot2)
    return __builtin_amdgcn_fdot2(__builtin_bit_cast(h2, a), __builtin_bit_cast(h2, b), c, false);
#else
    h2 x = __builtin_bit_cast(h2, a), y = __builtin_bit_cast(h2, b);
    return fmaf((float)x[0], (float)y[0], fmaf((float)x[1], (float)y[1], c));
#endif
}
__device__ __forceinline__ float fastrcp(float x) {
#if __has_builtin(__builtin_amdgcn_rcpf)
    return __builtin_amdgcn_rcpf(x);
#else
    return 1.0f / x;
#endif
}
__device__ __forceinline__ float sig_rcp(float x)  { return fastrcp(1.0f + __expf(-x)); }
__device__ __forceinline__ float tanh_rcp(float x) { return fmaf(2.0f, fastrcp(1.0f + __expf(-2.0f * x)), -1.0f); }
__device__ __forceinline__ half8_t cvt8(const float* p) {
    const float4* p4 = (const float4*)p;
    float4 a = p4[0], b = p4[1];
    return half8_t{ (_Float16)a.x, (_Float16)a.y, (_Float16)a.z, (_Float16)a.w,
                    (_Float16)b.x, (_Float16)b.y, (_Float16)b.z, (_Float16)b.w };
}

// Rare-path fallback: consumer computes gx[tlo..19] itself into ws (global),
// using sx LDS staging. Correct regardless of producer scheduling.
__device__ static void self_gx(float (*sx)[CELL], const int* net,
                               const float* emb_start, const float* emb_keys,
                               const float* W_ih, const float* b_ih, const float* b_hh,
                               float* gxp, int tid, int tlo)
{
    for (int i = tid; i < STEPS * CELL; i += 512) {
        const int t = i >> 7, k = i & 127;
        sx[t][k] = (t == 0) ? emb_start[k]
                 : emb_keys[((((t - 1) & 3) * 6) + net[t - 1]) * CELL + k];
    }
    __syncthreads();
    const int row = tid, tau = row >> 7, cell = row & 127;
    const float4* w4 = (const float4*)(W_ih + row * CELL);
    const float bias = b_ih[row] + b_hh[row];
    for (int t = tlo; t < STEPS; ++t) {
        const float4* x4 = (const float4*)sx[t];
        float a = 0.f, b = 0.f, c = 0.f, d = 0.f;
#pragma unroll 8
        for (int k = 0; k < 32; ++k) {
            float4 wv = w4[k], xv = x4[k];
            a = fmaf(wv.x, xv.x, a); b = fmaf(wv.y, xv.y, b);
            c = fmaf(wv.z, xv.z, c); d = fmaf(wv.w, xv.w, d);
        }
        gxp[t * 512 + cell * 4 + tau] = (a + b) + (c + d) + bias;
    }
    __threadfence();
    __syncthreads();
}

// ============================================================================
// R7 = exact revert to the R5 kernel (measured best, 92.5us).
// Single regular launch, 81 blocks x 512; producer->consumer flag handshake;
// two-phase gx gating (consumer starts after producers' first 10 steps --
// shortest post-fill tail measured); gx register-resident in two batches of
// 10 so the unrolled recurrence body has zero vector-memory ops and each
// __syncthreads' implicit vmcnt(0) drain is free.
// Session model (R6 rocprof): the kernel overlaps the harness poison fills
// (79.4us @ 84% HBM peak); only dispatch count and the post-fill tail are
// visible in dur_us. R6's single-phase gate lengthened the tail; reverted.
// ============================================================================
extern "C" __global__ void __launch_bounds__(512, 1)
nas_fused_kernel(const int* __restrict__ net,
                 const float* __restrict__ emb_start,
                 const float* __restrict__ emb_keys,
                 const float* __restrict__ fc_W,
                 const float* __restrict__ fc_b,
                 const float* __restrict__ W_ih,
                 const float* __restrict__ W_hh,
                 const float* __restrict__ b_ih,
                 const float* __restrict__ b_hh,
                 unsigned char* __restrict__ ws,
                 float* __restrict__ out)
{
    const int b   = blockIdx.x;
    const int tid = threadIdx.x;

    __shared__ __align__(16) float     sx[STEPS][CELL];   // producers + fallback
    __shared__ __align__(16) _Float16  hbuf[2 * 128];
    __shared__ __align__(16) unsigned  s_fcw2[24 * 64];
    __shared__ float s_fcb[24];
    __shared__ float llog[STEPS * 8];
    __shared__ int   s_fail[3];

    unsigned* flg = (unsigned*)(ws + WS_FLG);
    float*    gxp = (float*)(ws + WS_GX);

    if (b >= 1 && b <= 64) {
        // ---------------- gx producers: 8 rows/block, one row per wave ------
        for (int i = tid; i < STEPS * CELL; i += 512) {
            const int t = i >> 7, k = i & 127;
            sx[t][k] = (t == 0) ? emb_start[k]
                     : emb_keys[((((t - 1) & 3) * 6) + net[t - 1]) * CELL + k];
        }
        const int row  = (b - 1) * 8 + (tid >> 6);
        const int lane = tid & 63;
        const float2 w = ((const float2*)W_ih)[row * 64 + lane];
        const float bias = b_ih[row] + b_hh[row];
        __syncthreads();
        const int tau = row >> 7, cell = row & 127;
#pragma unroll
        for (int t = 0; t < 10; ++t) {
            const float2 xv = *(const float2*)&sx[t][lane * 2];
            float p = fmaf(w.x, xv.x, w.y * xv.y);
            p += __shfl_down(p, 32); p += __shfl_down(p, 16);
            p += __shfl_down(p, 8);  p += __shfl_down(p, 4);
            p += __shfl_down(p, 2);  p += __shfl_down(p, 1);
            if (lane == 0) gxp[t * 512 + cell * 4 + tau] = p + bias;
        }
        __syncthreads();   // all waves' t<10 stores drained
        if (tid == 0)
            __hip_atomic_store(&flg[16 + (b - 1)], MAGIC, __ATOMIC_RELEASE, __HIP_MEMORY_SCOPE_AGENT);
#pragma unroll
        for (int t = 10; t < STEPS; ++t) {
            const float2 xv = *(const float2*)&sx[t][lane * 2];
            float p = fmaf(w.x, xv.x, w.y * xv.y);
            p += __shfl_down(p, 32); p += __shfl_down(p, 16);
            p += __shfl_down(p, 8);  p += __shfl_down(p, 4);
            p += __shfl_down(p, 2);  p += __shfl_down(p, 1);
            if (lane == 0) gxp[t * 512 + cell * 4 + tau] = p + bias;
        }
        __syncthreads();
        if (tid == 0)
            __hip_atomic_store(&flg[80 + (b - 1)], MAGIC, __ATOMIC_RELEASE, __HIP_MEMORY_SCOPE_AGENT);
        return;
    } else if (b >= 65) {
        // ---------------- W_hh f16 fragment pack ----------------------------
        const int F   = (b - 65) * 512 + tid;        // 0..8191
        const int g   = F >> 9;                      // tau*4 + kc
        const int m   = F & 511;
        const int tau = g >> 2, kc = g & 3;
        const int rr  = ((m >> 6) << 4) + (m & 15);
        const int qd  = (m >> 4) & 3;
        const int k0  = kc * 32 + qd * 8;
        half8_t h8 = cvt8(W_hh + (tau * 128 + rr) * CELL + k0);
        ((uint4*)(ws + WS_WHH))[g * 512 + m] = __builtin_bit_cast(uint4, h8);
        __syncthreads();
        if (tid == 0)
            __hip_atomic_store(&flg[b - 65], MAGIC, __ATOMIC_RELEASE, __HIP_MEMORY_SCOPE_AGENT);
        return;
    }

    // ======================= consumer (block 0) =============================
    const int t0   = tid;
    const int wv   = t0 >> 6;
    const int lane = t0 & 63;
    const int quad = lane >> 4;
    const int lcol = lane & 15;
    const int rr0  = (wv << 4) + lcol;

    if (tid < 3) s_fail[tid] = 0;
    {   // fc pack into own LDS (cold 6 KB; overlaps whh wait)
        const float2* fw2 = (const float2*)fc_W;
        for (int i = tid; i < 24 * 64; i += 512) {
            const float2 w = fw2[i];
            s_fcw2[i] = packf2(w.x, w.y);
        }
        if (tid < 24)  s_fcb[tid] = fc_b[tid];
        if (tid < 128) hbuf[128 + tid] = (_Float16)0.0f;  // h(-1)=0 (parity 1)
    }

    // ---- wait: W_hh fragments ready ----
    if (tid < 16) {
        int budget = 1 << 17;
        while (__hip_atomic_load(&flg[tid], __ATOMIC_RELAXED, __HIP_MEMORY_SCOPE_AGENT) != MAGIC)
            if (--budget == 0) { atomicOr(&s_fail[0], 1); break; }
    }
    __syncthreads();                                  // also publishes fc/hbuf LDS
    __builtin_amdgcn_fence(__ATOMIC_ACQUIRE, "agent");

    half8_t bf0[4], bf1[4], bf2[4], bf3[4];
    if (s_fail[0] == 0) {
        const uint4* ws_whh = (const uint4*)(ws + WS_WHH);
#pragma unroll
        for (int kc = 0; kc < 4; ++kc) {
            bf0[kc] = __builtin_bit_cast(half8_t, ws_whh[(0 * 4 + kc) * 512 + t0]);
            bf1[kc] = __builtin_bit_cast(half8_t, ws_whh[(1 * 4 + kc) * 512 + t0]);
            bf2[kc] = __builtin_bit_cast(half8_t, ws_whh[(2 * 4 + kc) * 512 + t0]);
            bf3[kc] = __builtin_bit_cast(half8_t, ws_whh[(3 * 4 + kc) * 512 + t0]);
        }
    } else {                                          // timeout: pack ourselves
#pragma unroll
        for (int kc = 0; kc < 4; ++kc) {
            const int k0 = kc * 32 + quad * 8;
            bf0[kc] = cvt8(W_hh + (0 * 128 + rr0) * CELL + k0);
            bf1[kc] = cvt8(W_hh + (1 * 128 + rr0) * CELL + k0);
            bf2[kc] = cvt8(W_hh + (2 * 128 + rr0) * CELL + k0);
            bf3[kc] = cvt8(W_hh + (3 * 128 + rr0) * CELL + k0);
        }
    }

    // ---- wait: gx chunk A (t<10) ----
    if (tid < 64) {
        int budget = 1 << 17;
        while (__hip_atomic_load(&flg[16 + tid], __ATOMIC_RELAXED, __HIP_MEMORY_SCOPE_AGENT) != MAGIC)
            if (--budget == 0) { atomicOr(&s_fail[1], 1); break; }
    }
    __syncthreads();
    __builtin_amdgcn_fence(__ATOMIC_ACQUIRE, "agent");
    bool need_b = true;
    if (s_fail[1]) {                                   // timeout: compute all gx
        self_gx(sx, net, emb_start, emb_keys, W_ih, b_ih, b_hh, gxp, tid, 0);
        need_b = false;
    }

    const float* ws_gx = (const float*)(ws + WS_GX);
    // ---- batch A of gx into registers: 10 back-to-back loads, one wait ----
    floatx4 gxr[10];
#pragma unroll
    for (int i = 0; i < 10; ++i)
        gxr[i] = *(const floatx4*)&ws_gx[i * 512 + rr0 * 4];
    float c = 0.0f;

    // ============ proven recurrence loop (fully unrolled, no vmem) ==========
#pragma unroll
    for (int t = 0; t < STEPS; ++t) {
        const floatx4 gx = gxr[(t < 10) ? t : (t - 10)];   // static index (unrolled)

        if (t == 9) {                                  // gate + register batch B
            if (need_b) {
                if (tid < 64) {
                    int budget = 1 << 20;
                    while (__hip_atomic_load(&flg[80 + tid], __ATOMIC_RELAXED, __HIP_MEMORY_SCOPE_AGENT) != MAGIC)
                        if (--budget == 0) { atomicOr(&s_fail[2], 1); break; }
                }
                __syncthreads();
                __builtin_amdgcn_fence(__ATOMIC_ACQUIRE, "agent");
                if (s_fail[2])
                    self_gx(sx, net, emb_start, emb_keys, W_ih, b_ih, b_hh, gxp, tid, 10);
            }
#pragma unroll
            for (int i = 0; i < 10; ++i)               // issued before step-9 MFMAs
                gxr[i] = *(const floatx4*)&ws_gx[(10 + i) * 512 + rr0 * 4];
        }

        const uint4* hp4 = (const uint4*)(hbuf + (((t + 1) & 1) << 7));  // h(t-1)

        floatx4 a0a = { gx[0], 0, 0, 0 }, a0b = { 0, 0, 0, 0 };
        floatx4 a1a = { gx[1], 0, 0, 0 }, a1b = { 0, 0, 0, 0 };
        floatx4 a2a = { gx[2], 0, 0, 0 }, a2b = { 0, 0, 0, 0 };
        floatx4 a3a = { gx[3], 0, 0, 0 }, a3b = { 0, 0, 0, 0 };
        {
            uint4 u0 = hp4[(0 << 2) + quad], u1 = hp4[(1 << 2) + quad];
            uint4 u2 = hp4[(2 << 2) + quad], u3 = hp4[(3 << 2) + quad];
            half8_t f0 = __builtin_bit_cast(half8_t, u0), f1 = __builtin_bit_cast(half8_t, u1);
            half8_t f2 = __builtin_bit_cast(half8_t, u2), f3 = __builtin_bit_cast(half8_t, u3);
            a0a = __builtin_amdgcn_mfma_f32_16x16x32_f16(f0, bf0[0], a0a, 0, 0, 0);
            a1a = __builtin_amdgcn_mfma_f32_16x16x32_f16(f0, bf1[0], a1a, 0, 0, 0);
            a2a = __builtin_amdgcn_mfma_f32_16x16x32_f16(f0, bf2[0], a2a, 0, 0, 0);
            a3a = __builtin_amdgcn_mfma_f32_16x16x32_f16(f0, bf3[0], a3a, 0, 0, 0);
            a0b = __builtin_amdgcn_mfma_f32_16x16x32_f16(f1, bf0[1], a0b, 0, 0, 0);
            a1b = __builtin_amdgcn_mfma_f32_16x16x32_f16(f1, bf1[1], a1b, 0, 0, 0);
            a2b = __builtin_amdgcn_mfma_f32_16x16x32_f16(f1, bf2[1], a2b, 0, 0, 0);
            a3b = __builtin_amdgcn_mfma_f32_16x16x32_f16(f1, bf3[1], a3b, 0, 0, 0);
            a0a = __builtin_amdgcn_mfma_f32_16x16x32_f16(f2, bf0[2], a0a, 0, 0, 0);
            a1a = __builtin_amdgcn_mfma_f32_16x16x32_f16(f2, bf1[2], a1a, 0, 0, 0);
            a2a = __builtin_amdgcn_mfma_f32_16x16x32_f16(f2, bf2[2], a2a, 0, 0, 0);
            a3a = __builtin_amdgcn_mfma_f32_16x16x32_f16(f2, bf3[2], a3a, 0, 0, 0);
            a0b = __builtin_amdgcn_mfma_f32_16x16x32_f16(f3, bf0[3], a0b, 0, 0, 0);
            a1b = __builtin_amdgcn_mfma_f32_16x16x32_f16(f3, bf1[3], a1b, 0, 0, 0);
            a2b = __builtin_amdgcn_mfma_f32_16x16x32_f16(f3, bf2[3], a2b, 0, 0, 0);
            a3b = __builtin_amdgcn_mfma_f32_16x16x32_f16(f3, bf3[3], a3b, 0, 0, 0);
        }

        // heads of step t-1 on waves 0-5 quad 1, in the MFMA shadow (LDS reads)
        if (t >= 1 && wv < 6 && quad == 1) {
            const int li = lcol;
            const int hg = ((t - 1) & 3) * 6 + wv;
            const unsigned* hb = (const unsigned*)(hbuf + (((t + 1) & 1) << 7));
            const uint4 wpv = *(const uint4*)(s_fcw2 + hg * 64 + li * 4);
            float p = fdot2u(hb[li * 4],     wpv.x, 0.0f);
            p = fdot2u(hb[li * 4 + 1], wpv.y, p);
            p = fdot2u(hb[li * 4 + 2], wpv.z, p);
            p = fdot2u(hb[li * 4 + 3], wpv.w, p);
            p += __shfl_down(p, 8); p += __shfl_down(p, 4);
            p += __shfl_down(p, 2); p += __shfl_down(p, 1);
            if (li == 0) llog[(t - 1) * 8 + wv] = p + s_fcb[hg];
        }

        // full elementwise on every lane (gx in acc; no shuffles)
        {
            float ig = sig_rcp (a0a[0] + a0b[0]);
            float fg = sig_rcp (a1a[0] + a1b[0]);
            float gg = tanh_rcp(a2a[0] + a2b[0]);
            float og = sig_rcp (a3a[0] + a3b[0]);
            c = fg * c + ig * gg;
            float h = og * tanh_rcp(c);
            if (quad == 0)
                hbuf[((t & 1) << 7) + rr0] = (_Float16)h;
        }

        __syncthreads();
    }

    // ======== epilogue: head(19) + all 20 softmaxes ========
    if (wv < 6 && quad == 1) {
        const int li = lcol;
        const int hg = (19 & 3) * 6 + wv;
        const unsigned* hb = (const unsigned*)(hbuf + 128);   // h(19), parity 1
        const uint4 wpv = *(const uint4*)(s_fcw2 + hg * 64 + li * 4);
        float p = fdot2u(hb[li * 4],     wpv.x, 0.0f);
        p = fdot2u(hb[li * 4 + 1], wpv.y, p);
        p = fdot2u(hb[li * 4 + 2], wpv.z, p);
        p = fdot2u(hb[li * 4 + 3], wpv.w, p);
        p += __shfl_down(p, 8); p += __shfl_down(p, 4);
        p += __shfl_down(p, 2); p += __shfl_down(p, 1);
        if (li == 0) llog[19 * 8 + wv] = p + s_fcb[hg];
    }
    __syncthreads();
    if (t0 < STEPS * 6) {
        const int s = t0 / 6, k = t0 - s * 6;
        const float* L = llog + s * 8;
        float l0 = L[0], l1 = L[1], l2 = L[2], l3 = L[3], l4 = L[4], l5 = L[5];
        float m = fmaxf(fmaxf(fmaxf(l0, l1), fmaxf(l2, l3)), fmaxf(l4, l5));
        float e0 = __expf(l0 - m), e1 = __expf(l1 - m), e2 = __expf(l2 - m);
        float e3 = __expf(l3 - m), e4 = __expf(l4 - m), e5 = __expf(l5 - m);
        float sum = ((e0 + e1) + (e2 + e3)) + (e4 + e5);
        float mine = (k == 0) ? e0 : (k == 1) ? e1 : (k == 2) ? e2
                   : (k == 3) ? e3 : (k == 4) ? e4 : e5;
        out[t0] = mine / sum;
    }

    // reset flag slots for the next replay (producers all done: we waited)
    if (t0 < 144) flg[t0] = 0u;
    __syncthreads();
    if (t0 == 0) __builtin_amdgcn_fence(__ATOMIC_RELEASE, "agent");
}

// ============================================================================
// Fallback: proven mono kernel (used only if ws is too small).
// ============================================================================
extern "C" __global__ void __launch_bounds__(512, 1)
nas_policy_mono(const int* __restrict__ net,
                const float* __restrict__ emb_start,
                const float* __restrict__ emb_keys,
                const float* __restrict__ fc_W,
                const float* __restrict__ fc_b,
                const float* __restrict__ W_ih,
                const float* __restrict__ W_hh,
                const float* __restrict__ b_ih,
                const float* __restrict__ b_hh,
                float* __restrict__ out)
{
    const int t0   = threadIdx.x;
    const int wv   = t0 >> 6;
    const int lane = t0 & 63;
    const int quad = lane >> 4;
    const int lcol = lane & 15;

    __shared__ __align__(16) unsigned  s_xv2[32 * 68];
    __shared__ __align__(16) float     s_gx[STEPS * 512];
    __shared__ __align__(16) _Float16  hbuf[2 * 128];
    __shared__ unsigned s_fcw2[24 * 64];
    __shared__ float    s_fcb[24];
    __shared__ float    llog[STEPS * 8];

    for (int i = t0; i < STEPS * 64; i += 512) {
        const int m = i >> 6, j = i & 63;
        const float2* src = (m == 0) ? (const float2*)emb_start
            : (const float2*)(emb_keys + ((((m - 1) & 3) * 6) + net[m - 1]) * CELL);
        float2 v = src[j];
        s_xv2[m * 68 + j] = packf2(v.x, v.y);
    }
    {
        const float2* fw2 = (const float2*)fc_W;
        for (int i = t0; i < 24 * 64; i += 512) { float2 w = fw2[i]; s_fcw2[i] = packf2(w.x, w.y); }
    }
    if (t0 < 24)  s_fcb[t0] = fc_b[t0];
    if (t0 < 128) hbuf[128 + t0] = (_Float16)0.0f;

    const int rr0 = (wv << 4) + lcol;
    float biasx[4];
#pragma unroll
    for (int tau = 0; tau < 4; ++tau) {
        const int r = tau * 128 + rr0;
        biasx[tau] = b_ih[r] + b_hh[r];
    }

    __syncthreads();

    {
        half8_t bw[4][4];
#pragma unroll
        for (int kc = 0; kc < 4; ++kc) {
            const int k0 = kc * 32 + quad * 8;
#pragma unroll
            for (int tau = 0; tau < 4; ++tau)
                bw[kc][tau] = cvt8(W_ih + (tau * 128 + rr0) * CELL + k0);
        }
        floatx4 ax0[4] = { {0,0,0,0}, {0,0,0,0}, {0,0,0,0}, {0,0,0,0} };
        floatx4 ax1[4] = { {0,0,0,0}, {0,0,0,0}, {0,0,0,0}, {0,0,0,0} };
#pragma unroll
        for (int kc = 0; kc < 4; ++kc) {
            uint4 u0 = *(const uint4*)&s_xv2[lcol * 68 + kc * 16 + quad * 4];
            uint4 u1 = *(const uint4*)&s_xv2[(16 + lcol) * 68 + kc * 16 + quad * 4];
            half8_t a0f = __builtin_bit_cast(half8_t, u0);
            half8_t a1f = __builtin_bit_cast(half8_t, u1);
#pragma unroll
            for (int tau = 0; tau < 4; ++tau) {
                ax0[tau] = __builtin_amdgcn_mfma_f32_16x16x32_f16(a0f, bw[kc][tau], ax0[tau], 0, 0, 0);
                ax1[tau] = __builtin_amdgcn_mfma_f32_16x16x32_f16(a1f, bw[kc][tau], ax1[tau], 0, 0, 0);
            }
        }
#pragma unroll
        for (int tau = 0; tau < 4; ++tau) {
#pragma unroll
            for (int reg = 0; reg < 4; ++reg)
                s_gx[(quad * 4 + reg) * 512 + rr0 * 4 + tau] = ax0[tau][reg] + biasx[tau];
            if (quad == 0) {
#pragma unroll
                for (int reg = 0; reg < 4; ++reg)
                    s_gx[(16 + reg) * 512 + rr0 * 4 + tau] = ax1[tau][reg] + biasx[tau];
            }
        }
    }

    half8_t bf0[4], bf1[4], bf2[4], bf3[4];
#pragma unroll
    for (int kc = 0; kc < 4; ++kc) {
        const int k0 = kc * 32 + quad * 8;
        bf0[kc] = cvt8(W_hh + (0 * 128 + rr0) * CELL + k0);
        bf1[kc] = cvt8(W_hh + (1 * 128 + rr0) * CELL + k0);
        bf2[kc] = cvt8(W_hh + (2 * 128 + rr0) * CELL + k0);
        bf3[kc] = cvt8(W_hh + (3 * 128 + rr0) * CELL + k0);
    }

    float c = 0.0f;
    __syncthreads();

    for (int t = 0; t < STEPS; ++t) {
        const uint4* hp4 = (const uint4*)(hbuf + (((t + 1) & 1) << 7));
        floatx4 gx = *(const floatx4*)&s_gx[t * 512 + rr0 * 4];
        floatx4 a0a = {0,0,0,0}, a0b = {0,0,0,0}, a1a = {0,0,0,0}, a1b = {0,0,0,0};
        floatx4 a2a = {0,0,0,0}, a2b = {0,0,0,0}, a3a = {0,0,0,0}, a3b = {0,0,0,0};
        {
            uint4 u0 = hp4[(0 << 2) + quad], u1 = hp4[(1 << 2) + quad];
            uint4 u2 = hp4[(2 << 2) + quad], u3 = hp4[(3 << 2) + quad];
            half8_t f0 = __builtin_bit_cast(half8_t, u0), f1 = __builtin_bit_cast(half8_t, u1);
            half8_t f2 = __builtin_bit_cast(half8_t, u2), f3 = __builtin_bit_cast(half8_t, u3);
            a0a = __builtin_amdgcn_mfma_f32_16x16x32_f16(f0, bf0[0], a0a, 0, 0, 0);
            a1a = __builtin_amdgcn_mfma_f32_16x16x32_f16(f0, bf1[0], a1a, 0, 0, 0);
            a2a = __builtin_amdgcn_mfma_f32_16x16x32_f16(f0, bf2[0], a2a, 0, 0, 0);
            a3a = __builtin_amdgcn_mfma_f32_16x16x32_f16(f0, bf3[0], a3a, 0, 0, 0);
            a0b = __builtin_amdgcn_mfma_f32_16x16x32_f16(f1, bf0[1], a0b, 0, 0, 0);
            a1b = __builtin_amdgcn_mfma_f32_16x16x32_f16(f1, bf1[1], a1b, 0, 0, 0);
            a2b = __builtin_amdgcn_mfma_f32_16x16x32_f16(f1, bf2[1], a2b, 0, 0, 0);
            a3b = __builtin_amdgcn_mfma_f32_16x16x32_f16(f1, bf3[1], a3b, 0, 0, 0);
            a0a = __builtin_amdgcn_mfma_f32_16x16x32_f16(f2, bf0[2], a0a, 0, 0, 0);
            a1a = __builtin_amdgcn_mfma_f32_16x16x32_f16(f2, bf1[2], a1a, 0, 0, 0);
            a2a = __builtin_amdgcn_mfma_f32_16x16x32_f16(f2, bf2[2], a2a, 0, 0, 0);
            a3a = __builtin_amdgcn_mfma_f32_16x16x32_f16(f2, bf3[2], a3a, 0, 0, 0);
            a0b = __builtin_amdgcn_mfma_f32_16x16x32_f16(f3, bf0[3], a0b, 0, 0, 0);
            a1b = __builtin_amdgcn_mfma_f32_16x16x32_f16(f3, bf1[3], a1b, 0, 0, 0);
            a2b = __builtin_amdgcn_mfma_f32_16x16x32_f16(f3, bf2[3], a2b, 0, 0, 0);
            a3b = __builtin_amdgcn_mfma_f32_16x16x32_f16(f3, bf3[3], a3b, 0, 0, 0);
        }

        if (t >= 1 && wv < 6 && quad == 1) {
            const int li = lcol;
            const int hg = ((t - 1) & 3) * 6 + wv;
            const unsigned* hb = (const unsigned*)(hbuf + (((t + 1) & 1) << 7));
            const unsigned* wp = s_fcw2 + hg * 64 + li * 4;
            float p = fdot2u(hb[li * 4],     wp[0], 0.0f);
            p = fdot2u(hb[li * 4 + 1], wp[1], p);
            p = fdot2u(hb[li * 4 + 2], wp[2], p);
            p = fdot2u(hb[li * 4 + 3], wp[3], p);
            p += __shfl_down(p, 8); p += __shfl_down(p, 4);
            p += __shfl_down(p, 2); p += __shfl_down(p, 1);
            if (li == 0) llog[(t - 1) * 8 + wv] = p + s_fcb[hg];
        }

        {
            float ig = sig_rcp (a0a[0] + a0b[0] + gx[0]);
            float fg = sig_rcp (a1a[0] + a1b[0] + gx[1]);
            float gg = tanh_rcp(a2a[0] + a2b[0] + gx[2]);
            float og = sig_rcp (a3a[0] + a3b[0] + gx[3]);
            c = fg * c + ig * gg;
            float h = og * tanh_rcp(c);
            if (quad == 0)
                hbuf[((t & 1) << 7) + rr0] = (_Float16)h;
        }

        __syncthreads();
    }

    if (wv < 6 && quad == 1) {
        const int li = lcol;
        const int hg = (19 & 3) * 6 + wv;
        const unsigned* hb = (const unsigned*)(hbuf + 128);
        const unsigned* wp = s_fcw2 + hg * 64 + li * 4;
        float p = fdot2u(hb[li * 4],     wp[0], 0.0f);
        p = fdot2u(hb[li * 4 + 1], wp[1], p);
        p = fdot2u(hb[li * 4 + 2], wp[2], p);
        p = fdot2u(hb[li * 4 + 3], wp[3], p);
        p += __shfl_down(p, 8); p += __shfl_down(p, 4);
        p += __shfl_down(p, 2); p += __shfl_down(p, 1);
        if (li == 0) llog[19 * 8 + wv] = p + s_fcb[hg];
    }
    __syncthreads();
    if (t0 < STEPS * 6) {
        const int s = t0 / 6, k = t0 - s * 6;
        const float* L = llog + s * 8;
        float l0 = L[0], l1 = L[1], l2 = L[2], l3 = L[3], l4 = L[4], l5 = L[5];
        float m = fmaxf(fmaxf(fmaxf(l0, l1), fmaxf(l2, l3)), fmaxf(l4, l5));
        float e0 = __expf(l0 - m), e1 = __expf(l1 - m), e2 = __expf(l2 - m);
        float e3 = __expf(l3 - m), e4 = __expf(l4 - m), e5 = __expf(l5 - m);
        float sum = ((e0 + e1) + (e2 + e3)) + (e4 + e5);
        float mine = (k == 0) ? e0 : (k == 1) ? e1 : (k == 2) ? e2
                   : (k == 3) ? e3 : (k == 4) ? e4 : e5;
        out[t0] = mine / sum;
    }
}

extern "C" void kernel_launch(void* const* d_in, const int* in_sizes, int n_in,
                              void* d_out, int out_size, void* d_ws, size_t ws_size,
                              hipStream_t stream) {
    (void)in_sizes; (void)n_in; (void)out_size;
    const int*   net       = (const int*)d_in[0];
    // d_in[1] = reward, unused in forward
    const float* emb_start = (const float*)d_in[2];
    const float* emb_keys  = (const float*)d_in[3];
    const float* fc_W      = (const float*)d_in[4];
    const float* fc_b      = (const float*)d_in[5];
    const float* W_ih      = (const float*)d_in[6];
    const float* W_hh      = (const float*)d_in[7];
    const float* b_ih      = (const float*)d_in[8];
    const float* b_hh      = (const float*)d_in[9];
    float*       out       = (float*)d_out;

    if (d_ws != nullptr && ws_size >= (size_t)WS_NEED) {
        unsigned char* ws = (unsigned char*)d_ws;
        hipLaunchKernelGGL(nas_fused_kernel, dim3(81), dim3(512), 0, stream,
                           net, emb_start, emb_keys, fc_W, fc_b,
                           W_ih, W_hh, b_ih, b_hh, ws, out);
    } else {
        hipLaunchKernelGGL(nas_policy_mono, dim3(1), dim3(512), 0, stream,
                           net, emb_start, emb_keys, fc_W, fc_b,
                           W_ih, W_hh, b_ih, b_hh, out);
    }
}